// Round 1
// baseline (885.592 us; speedup 1.0000x reference)
//
#include <hip/hip_runtime.h>
#include <math.h>

#define NROWS 65536
#define KCB   1024
#define DDIM  256

#define BN 64
#define BK 128
#define BJ 32
#define MARGIN 0.01f

// d_out layout (floats):
//   [0, 16777216)          z_q_ste
//   16777216               vq_loss
//   [16777217, +65536)     indices (as float)
//   16842753               perplexity
//   16842754               codebook_usage
#define OUT_ZQ    0
#define OUT_LOSS  16777216
#define OUT_IDX   16777217
#define OUT_PERP  16842753
#define OUT_USAGE 16842754

// ---------------------------------------------------------------------------
// Kernel 1: codebook = normalize(lb @ W.T) * 16, computed in fp64.
// One block per codebook row k; thread t computes element i = t.
// ---------------------------------------------------------------------------
__global__ __launch_bounds__(256) void cb_kernel(const float* __restrict__ lb,
                                                 const float* __restrict__ W,
                                                 double* __restrict__ cb64,
                                                 float* __restrict__ cb32,
                                                 double* __restrict__ c264) {
  const int k = blockIdx.x;
  const int t = threadIdx.x;
  __shared__ float lb_sh[256];
  __shared__ float W_sh[256 * 66];   // pad 66 -> stride 2 mod 32, 2-way (free)
  __shared__ double red[256];

  lb_sh[t] = lb[k * 256 + t];

  double acc = 0.0;
  for (int jt = 0; jt < 4; ++jt) {
    __syncthreads();
    // stage W[0..255][jt*64 .. jt*64+63] (coalesced float4)
#pragma unroll
    for (int i = 0; i < 16; ++i) {
      int qid = t + 256 * i;
      int row = qid >> 4;
      int q   = qid & 15;
      float4 v = *(const float4*)&W[row * 256 + jt * 64 + q * 4];
      float* dst = &W_sh[row * 66 + q * 4];
      dst[0] = v.x; dst[1] = v.y; dst[2] = v.z; dst[3] = v.w;
    }
    __syncthreads();
#pragma unroll
    for (int jj = 0; jj < 64; ++jj) {
      acc += (double)lb_sh[jt * 64 + jj] * (double)W_sh[t * 66 + jj];
    }
  }

  // row norm of pre-normalized codebook
  red[t] = acc * acc;
  __syncthreads();
  for (int s = 128; s > 0; s >>= 1) {
    if (t < s) red[t] += red[t + s];
    __syncthreads();
  }
  double norm  = sqrt(red[0]);
  double scale = 16.0 / fmax(norm, 1e-12);
  double v     = acc * scale;
  cb64[k * 256 + t] = v;
  cb32[k * 256 + t] = (float)v;

  __syncthreads();               // everyone done reading red[0]
  red[t] = v * v;
  __syncthreads();
  for (int s = 128; s > 0; s >>= 1) {
    if (t < s) red[t] += red[t + s];
    __syncthreads();
  }
  if (t == 0) c264[k] = red[0];
}

// ---------------------------------------------------------------------------
// Kernel 2: per-row argmax of z . cb^T in fp32 with (max, idx, 2nd-max)
// tracking. 64 rows x 128 codes per block, 4x8 register tile per thread.
// Rows with max-gap < MARGIN get flagged for fp64 refinement.
// ---------------------------------------------------------------------------
__global__ __launch_bounds__(256) void argmax_kernel(const float* __restrict__ z,
                                                     const float* __restrict__ cb32,
                                                     float* __restrict__ out_idx,
                                                     int* __restrict__ idx_int,
                                                     int* __restrict__ flagc,
                                                     int* __restrict__ flagr) {
  const int t    = threadIdx.x;
  const int row0 = blockIdx.x * BN;
  const int tr   = t >> 4;      // 0..15 -> rows tr*4 .. tr*4+3
  const int tc   = t & 15;      // 0..15 -> cols tc*8 .. tc*8+7
  const int r0   = tr * 4;
  const int c0   = tc * 8;

  __shared__ float z_sh[BJ][BN];     // transposed: [j][row]
  __shared__ float c_sh[BJ][BK];     // transposed: [j][code]

  float m1[4], m2[4];
  int   i1[4];
#pragma unroll
  for (int r = 0; r < 4; ++r) { m1[r] = -3.0e38f; m2[r] = -3.0e38f; i1[r] = 0; }

  for (int kt = 0; kt < KCB / BK; ++kt) {
    float acc[4][8];
#pragma unroll
    for (int r = 0; r < 4; ++r)
#pragma unroll
      for (int c = 0; c < 8; ++c) acc[r][c] = 0.f;

    for (int jt = 0; jt < DDIM / BJ; ++jt) {
      __syncthreads();   // previous tile's compute done before overwrite
      // stage z tile: 64 rows x 32 j, transposed into LDS
#pragma unroll
      for (int i = 0; i < 2; ++i) {
        int qid = t + 256 * i;
        int rr  = qid >> 3;
        int q   = qid & 7;
        float4 v = *(const float4*)&z[(row0 + rr) * DDIM + jt * BJ + q * 4];
        z_sh[q * 4 + 0][rr] = v.x;
        z_sh[q * 4 + 1][rr] = v.y;
        z_sh[q * 4 + 2][rr] = v.z;
        z_sh[q * 4 + 3][rr] = v.w;
      }
      // stage cb tile: 128 codes x 32 j, transposed
#pragma unroll
      for (int i = 0; i < 4; ++i) {
        int qid = t + 256 * i;
        int cc  = qid >> 3;
        int q   = qid & 7;
        float4 v = *(const float4*)&cb32[(kt * BK + cc) * DDIM + jt * BJ + q * 4];
        c_sh[q * 4 + 0][cc] = v.x;
        c_sh[q * 4 + 1][cc] = v.y;
        c_sh[q * 4 + 2][cc] = v.z;
        c_sh[q * 4 + 3][cc] = v.w;
      }
      __syncthreads();

#pragma unroll
      for (int j = 0; j < BJ; ++j) {
        const float4 zv  = *(const float4*)&z_sh[j][r0];
        const float4 ca  = *(const float4*)&c_sh[j][c0];
        const float4 cbv = *(const float4*)&c_sh[j][c0 + 4];
        const float zr_[4] = {zv.x, zv.y, zv.z, zv.w};
        const float cc_[8] = {ca.x, ca.y, ca.z, ca.w, cbv.x, cbv.y, cbv.z, cbv.w};
#pragma unroll
        for (int r = 0; r < 4; ++r)
#pragma unroll
          for (int c = 0; c < 8; ++c)
            acc[r][c] = fmaf(zr_[r], cc_[c], acc[r][c]);
      }
    }

    // epilogue: fold this k-tile into the running (m1, i1, m2) per row
#pragma unroll
    for (int r = 0; r < 4; ++r) {
      float lm1 = acc[r][0];
      int   li1 = kt * BK + c0;
      float lm2 = -3.0e38f;
#pragma unroll
      for (int c = 1; c < 8; ++c) {
        float v = acc[r][c];
        int  kk = kt * BK + c0 + c;
        if (v > lm1) { lm2 = lm1; lm1 = v; li1 = kk; }
        else          lm2 = fmaxf(lm2, v);
      }
      // reduce across the 16 col-group lanes (same wave: xor 1,2,4,8)
#pragma unroll
      for (int off = 1; off <= 8; off <<= 1) {
        float om1 = __shfl_xor(lm1, off);
        float om2 = __shfl_xor(lm2, off);
        int   oi1 = __shfl_xor(li1, off);
        if (om1 > lm1 || (om1 == lm1 && oi1 < li1)) {
          lm2 = fmaxf(lm1, om2);
          lm1 = om1; li1 = oi1;
        } else {
          lm2 = fmaxf(lm2, om1);
        }
      }
      if (lm1 > m1[r] || (lm1 == m1[r] && li1 < i1[r])) {
        m2[r] = fmaxf(m1[r], lm2);
        m1[r] = lm1; i1[r] = li1;
      } else {
        m2[r] = fmaxf(m2[r], lm1);
      }
    }
  }

  if (tc == 0) {
#pragma unroll
    for (int r = 0; r < 4; ++r) {
      int row = row0 + r0 + r;
      out_idx[row] = (float)i1[r];
      idx_int[row] = i1[r];
      if (m1[r] - m2[r] < MARGIN) {
        int p = atomicAdd(flagc, 1);
        flagr[p] = row;
      }
    }
  }
}

// ---------------------------------------------------------------------------
// Kernel 3: exact fp64 re-solve of flagged (near-tie) rows over all K.
// score = 2*dot - ||c||^2 (equivalent to -distance up to per-row constant).
// ---------------------------------------------------------------------------
__global__ __launch_bounds__(256) void refine_kernel(const float* __restrict__ z,
                                                     const double* __restrict__ cb64,
                                                     const double* __restrict__ c264,
                                                     const int* __restrict__ flagc,
                                                     const int* __restrict__ flagr,
                                                     int* __restrict__ idx_int,
                                                     float* __restrict__ out_idx) {
  const int cnt  = *flagc;
  const int t    = threadIdx.x;
  const int w    = t >> 6;
  const int lane = t & 63;
  __shared__ double bs[4];
  __shared__ int    bi[4];

  for (int fi = blockIdx.x; fi < cnt; fi += gridDim.x) {
    const int row = flagr[fi];
    double zr[4];
#pragma unroll
    for (int jj = 0; jj < 4; ++jj)
      zr[jj] = (double)z[row * DDIM + jj * 64 + lane];

    double best = -1e300;
    int bidx = 0;
    for (int k = w * 256; k < w * 256 + 256; ++k) {
      double p = 0.0;
#pragma unroll
      for (int jj = 0; jj < 4; ++jj)
        p += zr[jj] * cb64[k * DDIM + jj * 64 + lane];
#pragma unroll
      for (int off = 32; off > 0; off >>= 1) p += __shfl_xor(p, off);
      double sc = 2.0 * p - c264[k];
      if (sc > best) { best = sc; bidx = k; }   // ascending k: tie keeps smaller
    }
    if (lane == 0) { bs[w] = best; bi[w] = bidx; }
    __syncthreads();
    if (t == 0) {
      double B = bs[0]; int I = bi[0];
#pragma unroll
      for (int w2 = 1; w2 < 4; ++w2) {
        if (bs[w2] > B || (bs[w2] == B && bi[w2] < I)) { B = bs[w2]; I = bi[w2]; }
      }
      idx_int[row] = I;
      out_idx[row] = (float)I;
    }
    __syncthreads();
  }
}

// ---------------------------------------------------------------------------
// Kernel 4: gather z_q, accumulate mse (fp64 atomic), histogram counts.
// One wave per row, 4 rows per block.
// ---------------------------------------------------------------------------
__global__ __launch_bounds__(256) void gather_kernel(const float* __restrict__ z,
                                                     const float* __restrict__ cb32,
                                                     const int* __restrict__ idx_int,
                                                     float* __restrict__ zq,
                                                     double* __restrict__ mse_acc,
                                                     int* __restrict__ counts) {
  const int t    = threadIdx.x;
  const int w    = t >> 6;
  const int lane = t & 63;
  const int row  = blockIdx.x * 4 + w;
  const int idx  = idx_int[row];

  const float4 c  = *(const float4*)&cb32[idx * DDIM + lane * 4];
  const float4 ze = *(const float4*)&z[row * DDIM + lane * 4];
  *(float4*)&zq[row * DDIM + lane * 4] = c;

  double s = 0.0, d;
  d = (double)c.x - (double)ze.x; s += d * d;
  d = (double)c.y - (double)ze.y; s += d * d;
  d = (double)c.z - (double)ze.z; s += d * d;
  d = (double)c.w - (double)ze.w; s += d * d;
#pragma unroll
  for (int off = 32; off > 0; off >>= 1) s += __shfl_xor(s, off);

  __shared__ double partial[4];
  if (lane == 0) {
    partial[w] = s;
    atomicAdd(&counts[idx], 1);
  }
  __syncthreads();
  if (t == 0) atomicAdd(mse_acc, partial[0] + partial[1] + partial[2] + partial[3]);
}

// ---------------------------------------------------------------------------
// Kernel 5: scalars -- vq_loss, perplexity, codebook_usage.
// ---------------------------------------------------------------------------
__global__ __launch_bounds__(256) void finalize_kernel(const int* __restrict__ counts,
                                                       const double* __restrict__ mse_acc,
                                                       float* __restrict__ out) {
  const int t = threadIdx.x;
  double ent = 0.0;
  int used = 0;
#pragma unroll
  for (int i = t; i < KCB; i += 256) {
    int c = counts[i];
    if (c > 0) used++;
    double p = (double)c / (double)NROWS;
    ent += p * log(p + 1e-10);
  }
  __shared__ double se[256];
  __shared__ int    su[256];
  se[t] = ent; su[t] = used;
  __syncthreads();
  for (int s = 128; s > 0; s >>= 1) {
    if (t < s) { se[t] += se[t + s]; su[t] += su[t + s]; }
    __syncthreads();
  }
  if (t == 0) {
    double mse = *mse_acc / ((double)NROWS * (double)DDIM);
    out[OUT_LOSS]  = (float)(1.25 * mse);      // mse + COMMIT*mse
    out[OUT_PERP]  = (float)exp(-se[0]);
    out[OUT_USAGE] = (float)((double)su[0] / (double)KCB);
  }
}

// ---------------------------------------------------------------------------
extern "C" void kernel_launch(void* const* d_in, const int* in_sizes, int n_in,
                              void* d_out, int out_size, void* d_ws, size_t ws_size,
                              hipStream_t stream) {
  const float* z  = (const float*)d_in[0];   // [65536][256]
  const float* lb = (const float*)d_in[1];   // [1024][256]
  const float* W  = (const float*)d_in[2];   // [256][256]
  float* out = (float*)d_out;

  char* ws = (char*)d_ws;
  double* cb64   = (double*)(ws + 0x000000);   // 2 MB
  double* c264   = (double*)(ws + 0x200000);   // 8 KB
  double* mseacc = (double*)(ws + 0x202000);   // 8 B
  float*  cb32   = (float*) (ws + 0x202100);   // 1 MB (16B aligned)
  int*    idxi   = (int*)   (ws + 0x302100);   // 256 KB
  int*    flagc  = (int*)   (ws + 0x342100);   // 4 B
  int*    flagr  = (int*)   (ws + 0x342200);   // 256 KB
  int*    counts = (int*)   (ws + 0x382200);   // 4 KB
  // total ~3.6 MB of workspace

  hipMemsetAsync(flagc, 0, 4, stream);
  hipMemsetAsync(counts, 0, KCB * sizeof(int), stream);
  hipMemsetAsync(mseacc, 0, sizeof(double), stream);

  cb_kernel<<<KCB, 256, 0, stream>>>(lb, W, cb64, cb32, c264);
  argmax_kernel<<<NROWS / BN, 256, 0, stream>>>(z, cb32, out + OUT_IDX, idxi, flagc, flagr);
  refine_kernel<<<512, 256, 0, stream>>>(z, cb64, c264, flagc, flagr, idxi, out + OUT_IDX);
  gather_kernel<<<NROWS / 4, 256, 0, stream>>>(z, cb32, idxi, out + OUT_ZQ, mseacc, counts);
  finalize_kernel<<<1, 256, 0, stream>>>(counts, mseacc, out);
}

// Round 2
// 614.452 us; speedup vs baseline: 1.4413x; 1.4413x over previous
//
#include <hip/hip_runtime.h>
#include <math.h>

typedef unsigned int uint;
typedef unsigned short ushort;

#define NROWS 65536
#define KCB   1024
#define DDIM  256
#define MARGIN 0.01f

// d_out layout (floats)
#define OUT_ZQ    0
#define OUT_LOSS  16777216
#define OUT_IDX   16777217
#define OUT_PERP  16842753
#define OUT_USAGE 16842754

typedef __attribute__((ext_vector_type(8)))  short s16x8;
typedef __attribute__((ext_vector_type(16))) float f32x16;

__device__ __forceinline__ ushort bf16rne(float x) {
  uint u = __float_as_uint(x);
  return (ushort)((u + 0x7FFFu + ((u >> 16) & 1u)) >> 16);
}

// ---------------------------------------------------------------------------
// Kernel 1: codebook = normalize(lb @ W.T) * 16 in fp64; emit fp64, fp32,
// and bf16 hi/lo split copies.
// ---------------------------------------------------------------------------
__global__ __launch_bounds__(256) void cb_kernel(const float* __restrict__ lb,
                                                 const float* __restrict__ W,
                                                 double* __restrict__ cb64,
                                                 float* __restrict__ cb32,
                                                 double* __restrict__ c264,
                                                 ushort* __restrict__ ch,
                                                 ushort* __restrict__ cl) {
  const int k = blockIdx.x;
  const int t = threadIdx.x;
  __shared__ float lb_sh[256];
  __shared__ float W_sh[256 * 66];
  __shared__ double red[256];

  lb_sh[t] = lb[k * 256 + t];

  double acc = 0.0;
  for (int jt = 0; jt < 4; ++jt) {
    __syncthreads();
#pragma unroll
    for (int i = 0; i < 16; ++i) {
      int qid = t + 256 * i;
      int row = qid >> 4;
      int q   = qid & 15;
      float4 v = *(const float4*)&W[row * 256 + jt * 64 + q * 4];
      float* dst = &W_sh[row * 66 + q * 4];
      dst[0] = v.x; dst[1] = v.y; dst[2] = v.z; dst[3] = v.w;
    }
    __syncthreads();
#pragma unroll
    for (int jj = 0; jj < 64; ++jj) {
      acc += (double)lb_sh[jt * 64 + jj] * (double)W_sh[t * 66 + jj];
    }
  }

  red[t] = acc * acc;
  __syncthreads();
  for (int s = 128; s > 0; s >>= 1) {
    if (t < s) red[t] += red[t + s];
    __syncthreads();
  }
  double norm  = sqrt(red[0]);
  double scale = 16.0 / fmax(norm, 1e-12);
  double v     = acc * scale;
  cb64[k * 256 + t] = v;
  float cf = (float)v;
  cb32[k * 256 + t] = cf;
  ushort hh = bf16rne(cf);
  float  hf = __uint_as_float((uint)hh << 16);
  ch[k * 256 + t] = hh;
  cl[k * 256 + t] = bf16rne(cf - hf);

  __syncthreads();
  red[t] = v * v;
  __syncthreads();
  for (int s = 128; s > 0; s >>= 1) {
    if (t < s) red[t] += red[t + s];
    __syncthreads();
  }
  if (t == 0) c264[k] = red[0];
}

// ---------------------------------------------------------------------------
// Kernel 1b: split z fp32 -> z_hi + z_lo bf16 (memory-bound pre-pass).
// ---------------------------------------------------------------------------
__global__ __launch_bounds__(256) void zsplit_kernel(const float* __restrict__ z,
                                                     ushort* __restrict__ zhi,
                                                     ushort* __restrict__ zlo) {
  int i = blockIdx.x * 256 + threadIdx.x;
  const int stride = gridDim.x * 256;
  const int nq = NROWS * DDIM / 4;
  for (; i < nq; i += stride) {
    float4 v = *(const float4*)&z[i * 4];
    ushort4 h, l;
    h.x = bf16rne(v.x); l.x = bf16rne(v.x - __uint_as_float((uint)h.x << 16));
    h.y = bf16rne(v.y); l.y = bf16rne(v.y - __uint_as_float((uint)h.y << 16));
    h.z = bf16rne(v.z); l.z = bf16rne(v.z - __uint_as_float((uint)h.z << 16));
    h.w = bf16rne(v.w); l.w = bf16rne(v.w - __uint_as_float((uint)h.w << 16));
    *(ushort4*)&zhi[i * 4] = h;
    *(ushort4*)&zlo[i * 4] = l;
  }
}

// ---------------------------------------------------------------------------
// Kernel 2: MFMA argmax GEMM. scores = z . cb^T via bf16 split
// (zh*ch + zl*ch + zh*cl). Block: 128 rows x 128 codes, 4 waves (2m x 2n),
// each wave 64x64 via 2x2 mfma_f32_32x32x16_bf16 fragments. BK=32.
// LDS tiles [128][32] bf16, linear 64B rows; quad s of row r stored at slot
// s^(r&3) (swizzle applied on the *global source* address so
// global_load_lds's linear lane*16 dest works -- rule 21).
// Epilogue: per-row (m1, i1, m2) over this block's 2x64-code chunks ->
// partial arrays [16 chunks][NROWS].
// ---------------------------------------------------------------------------
template <bool PRESPLIT>
__global__ __launch_bounds__(256) void argmax_mfma(const float* __restrict__ z,
                                                   const ushort* __restrict__ zhi,
                                                   const ushort* __restrict__ zlo,
                                                   const ushort* __restrict__ ch,
                                                   const ushort* __restrict__ cl,
                                                   float* __restrict__ pm1,
                                                   float* __restrict__ pm2,
                                                   int* __restrict__ pi1) {
  const int t    = threadIdx.x;
  const int lane = t & 63;
  const int w    = t >> 6;
  const int wm   = w >> 1, wn = w & 1;
  const int mtile = blockIdx.x >> 3;
  const int ntile = blockIdx.x & 7;

  __shared__ alignas(128) char smem[32768];
  // tile offsets: ZH=0, ZL=8192, CH=16384, CL=24576

  f32x16 a00 = 0.0f, a01 = 0.0f, a10 = 0.0f, a11 = 0.0f;

  for (int kt = 0; kt < 8; ++kt) {
    __syncthreads();
    if (PRESPLIT) {
      // wave w stages tile w: 8 x global_load_lds dwordx4 (1 KB each)
      const ushort* sb = (w == 0) ? zhi : (w == 1) ? zlo : (w == 2) ? ch : cl;
      const int rowbase = (w < 2) ? (mtile * 128) : (ntile * 128);
      char* dstbase = smem + w * 8192;
      const int r = lane >> 2;
      const int q = lane & 3;
#pragma unroll
      for (int i = 0; i < 8; ++i) {
        int rr = i * 16 + r;
        int qs = q ^ (rr & 3);
        const ushort* src = sb + (size_t)(rowbase + rr) * 256 + kt * 32 + qs * 8;
        __builtin_amdgcn_global_load_lds((const __attribute__((address_space(1))) void*)src,
                                         (__attribute__((address_space(3))) void*)(dstbase + i * 1024),
                                         16, 0, 0);
      }
    } else {
      // cb tiles via global_load_lds: waves 0,1 -> CH; waves 2,3 -> CL
      {
        const ushort* sb = (w < 2) ? ch : cl;
        char* dstbase = smem + ((w < 2) ? 16384 : 24576) + (w & 1) * 4096;
        const int r = lane >> 2, q = lane & 3;
#pragma unroll
        for (int i = 0; i < 4; ++i) {
          int rr = (w & 1) * 64 + i * 16 + r;
          int qs = q ^ (rr & 3);
          const ushort* src = sb + (size_t)(ntile * 128 + rr) * 256 + kt * 32 + qs * 8;
          __builtin_amdgcn_global_load_lds((const __attribute__((address_space(1))) void*)src,
                                           (__attribute__((address_space(3))) void*)(dstbase + i * 1024),
                                           16, 0, 0);
        }
      }
      // z tiles: load fp32, split in-register, write swizzled b128s
      {
        const int r = t >> 1, kh = t & 1;
        const float* zp = z + (size_t)(mtile * 128 + r) * 256 + kt * 32 + kh * 16;
        float4 f0 = *(const float4*)(zp);
        float4 f1 = *(const float4*)(zp + 4);
        float4 f2 = *(const float4*)(zp + 8);
        float4 f3 = *(const float4*)(zp + 12);
        float xs[16] = {f0.x, f0.y, f0.z, f0.w, f1.x, f1.y, f1.z, f1.w,
                        f2.x, f2.y, f2.z, f2.w, f3.x, f3.y, f3.z, f3.w};
        s16x8 h0, l0, h1, l1;
#pragma unroll
        for (int e = 0; e < 8; ++e) {
          ushort hh = bf16rne(xs[e]);
          h0[e] = (short)hh;
          l0[e] = (short)bf16rne(xs[e] - __uint_as_float((uint)hh << 16));
        }
#pragma unroll
        for (int e = 0; e < 8; ++e) {
          ushort hh = bf16rne(xs[8 + e]);
          h1[e] = (short)hh;
          l1[e] = (short)bf16rne(xs[8 + e] - __uint_as_float((uint)hh << 16));
        }
        const int s0 = kh * 2, s1 = kh * 2 + 1;
        *(s16x8*)(smem + 0    + r * 64 + ((s0 ^ (r & 3)) * 16)) = h0;
        *(s16x8*)(smem + 8192 + r * 64 + ((s0 ^ (r & 3)) * 16)) = l0;
        *(s16x8*)(smem + 0    + r * 64 + ((s1 ^ (r & 3)) * 16)) = h1;
        *(s16x8*)(smem + 8192 + r * 64 + ((s1 ^ (r & 3)) * 16)) = l1;
      }
    }
    __syncthreads();

#pragma unroll
    for (int ks = 0; ks < 2; ++ks) {
      const int s  = ks * 2 + (lane >> 5);
      const int ra = lane & 31;
      auto frag = [&](int base, int row) -> s16x8 {
        return *(const s16x8*)(smem + base + row * 64 + ((s ^ (row & 3)) * 16));
      };
      s16x8 ah0 = frag(0,     wm * 64 + ra);
      s16x8 ah1 = frag(0,     wm * 64 + 32 + ra);
      s16x8 al0 = frag(8192,  wm * 64 + ra);
      s16x8 al1 = frag(8192,  wm * 64 + 32 + ra);
      s16x8 bh0 = frag(16384, wn * 64 + ra);
      s16x8 bh1 = frag(16384, wn * 64 + 32 + ra);
      s16x8 bl0 = frag(24576, wn * 64 + ra);
      s16x8 bl1 = frag(24576, wn * 64 + 32 + ra);
      a00 = __builtin_amdgcn_mfma_f32_32x32x16_bf16(ah0, bh0, a00, 0, 0, 0);
      a01 = __builtin_amdgcn_mfma_f32_32x32x16_bf16(ah0, bh1, a01, 0, 0, 0);
      a10 = __builtin_amdgcn_mfma_f32_32x32x16_bf16(ah1, bh0, a10, 0, 0, 0);
      a11 = __builtin_amdgcn_mfma_f32_32x32x16_bf16(ah1, bh1, a11, 0, 0, 0);
      a00 = __builtin_amdgcn_mfma_f32_32x32x16_bf16(al0, bh0, a00, 0, 0, 0);
      a01 = __builtin_amdgcn_mfma_f32_32x32x16_bf16(al0, bh1, a01, 0, 0, 0);
      a10 = __builtin_amdgcn_mfma_f32_32x32x16_bf16(al1, bh0, a10, 0, 0, 0);
      a11 = __builtin_amdgcn_mfma_f32_32x32x16_bf16(al1, bh1, a11, 0, 0, 0);
      a00 = __builtin_amdgcn_mfma_f32_32x32x16_bf16(ah0, bl0, a00, 0, 0, 0);
      a01 = __builtin_amdgcn_mfma_f32_32x32x16_bf16(ah0, bl1, a01, 0, 0, 0);
      a10 = __builtin_amdgcn_mfma_f32_32x32x16_bf16(ah1, bl0, a10, 0, 0, 0);
      a11 = __builtin_amdgcn_mfma_f32_32x32x16_bf16(ah1, bl1, a11, 0, 0, 0);
    }
  }

  // Epilogue: per output row, fold 2 col-fragments + 32-lane butterfly ->
  // (m1, i1, m2) for this block's 64-code chunk (chunk = ntile*2 + wn).
  // C/D layout (verified m74/m101): col = lane&31, row = (p&3)+8*(p>>2)+4*(lane>>5).
#define EPI(ACC0, ACC1, MSBASE)                                                \
  {                                                                            \
    _Pragma("unroll") for (int p = 0; p < 16; ++p) {                           \
      float v0 = ACC0[p], v1 = ACC1[p];                                        \
      int   c0 = ntile * 128 + wn * 64 + (lane & 31);                          \
      float lm1, lm2;                                                          \
      int   li1;                                                               \
      if (v1 > v0) { lm1 = v1; li1 = c0 + 32; lm2 = v0; }                      \
      else         { lm1 = v0; li1 = c0;      lm2 = v1; }                      \
      _Pragma("unroll") for (int off = 1; off <= 16; off <<= 1) {              \
        float om1 = __shfl_xor(lm1, off);                                      \
        float om2 = __shfl_xor(lm2, off);                                      \
        int   oi1 = __shfl_xor(li1, off);                                      \
        if (om1 > lm1 || (om1 == lm1 && oi1 < li1)) {                          \
          lm2 = fmaxf(lm1, om2); lm1 = om1; li1 = oi1;                         \
        } else {                                                               \
          lm2 = fmaxf(lm2, om1);                                               \
        }                                                                      \
      }                                                                        \
      if ((lane & 31) == 0) {                                                  \
        int row = mtile * 128 + wm * 64 + MSBASE + (p & 3) + 8 * (p >> 2) +    \
                  4 * (lane >> 5);                                             \
        int chunk = ntile * 2 + wn;                                            \
        pm1[chunk * NROWS + row] = lm1;                                        \
        pm2[chunk * NROWS + row] = lm2;                                        \
        pi1[chunk * NROWS + row] = li1;                                        \
      }                                                                        \
    }                                                                          \
  }
  EPI(a00, a01, 0);
  EPI(a10, a11, 32);
#undef EPI
}

// ---------------------------------------------------------------------------
// Kernel 2b: fold the 16 per-chunk partials -> final index; flag near-ties.
// ---------------------------------------------------------------------------
__global__ __launch_bounds__(256) void reduce_kernel(const float* __restrict__ pm1,
                                                     const float* __restrict__ pm2,
                                                     const int* __restrict__ pi1,
                                                     float* __restrict__ out_idx,
                                                     int* __restrict__ idx_int,
                                                     int* __restrict__ flagc,
                                                     int* __restrict__ flagr) {
  const int row = blockIdx.x * 256 + threadIdx.x;
  float M1 = pm1[row];
  float M2 = pm2[row];
  int   I1 = pi1[row];
#pragma unroll
  for (int c = 1; c < 16; ++c) {
    float m1c = pm1[c * NROWS + row];
    float m2c = pm2[c * NROWS + row];
    int   i1c = pi1[c * NROWS + row];
    if (m1c > M1 || (m1c == M1 && i1c < I1)) {
      M2 = fmaxf(M1, m2c); M1 = m1c; I1 = i1c;
    } else {
      M2 = fmaxf(M2, m1c);
    }
  }
  idx_int[row] = I1;
  out_idx[row] = (float)I1;
  if (M1 - M2 < MARGIN) {
    int p = atomicAdd(flagc, 1);
    flagr[p] = row;
  }
}

// ---------------------------------------------------------------------------
// Kernel 3: exact fp64 re-solve of flagged rows (unchanged, passed round 1).
// ---------------------------------------------------------------------------
__global__ __launch_bounds__(256) void refine_kernel(const float* __restrict__ z,
                                                     const double* __restrict__ cb64,
                                                     const double* __restrict__ c264,
                                                     const int* __restrict__ flagc,
                                                     const int* __restrict__ flagr,
                                                     int* __restrict__ idx_int,
                                                     float* __restrict__ out_idx) {
  const int cnt  = *flagc;
  const int t    = threadIdx.x;
  const int w    = t >> 6;
  const int lane = t & 63;
  __shared__ double bs[4];
  __shared__ int    bi[4];

  for (int fi = blockIdx.x; fi < cnt; fi += gridDim.x) {
    const int row = flagr[fi];
    double zr[4];
#pragma unroll
    for (int jj = 0; jj < 4; ++jj)
      zr[jj] = (double)z[row * DDIM + jj * 64 + lane];

    double best = -1e300;
    int bidx = 0;
    for (int k = w * 256; k < w * 256 + 256; ++k) {
      double p = 0.0;
#pragma unroll
      for (int jj = 0; jj < 4; ++jj)
        p += zr[jj] * cb64[k * DDIM + jj * 64 + lane];
#pragma unroll
      for (int off = 32; off > 0; off >>= 1) p += __shfl_xor(p, off);
      double sc = 2.0 * p - c264[k];
      if (sc > best) { best = sc; bidx = k; }
    }
    if (lane == 0) { bs[w] = best; bi[w] = bidx; }
    __syncthreads();
    if (t == 0) {
      double B = bs[0]; int I = bi[0];
#pragma unroll
      for (int w2 = 1; w2 < 4; ++w2) {
        if (bs[w2] > B || (bs[w2] == B && bi[w2] < I)) { B = bs[w2]; I = bi[w2]; }
      }
      idx_int[row] = I;
      out_idx[row] = (float)I;
    }
    __syncthreads();
  }
}

// ---------------------------------------------------------------------------
// Kernel 4: gather z_q, mse accumulation, histogram (unchanged).
// ---------------------------------------------------------------------------
__global__ __launch_bounds__(256) void gather_kernel(const float* __restrict__ z,
                                                     const float* __restrict__ cb32,
                                                     const int* __restrict__ idx_int,
                                                     float* __restrict__ zq,
                                                     double* __restrict__ mse_acc,
                                                     int* __restrict__ counts) {
  const int t    = threadIdx.x;
  const int w    = t >> 6;
  const int lane = t & 63;
  const int row  = blockIdx.x * 4 + w;
  const int idx  = idx_int[row];

  const float4 c  = *(const float4*)&cb32[idx * DDIM + lane * 4];
  const float4 ze = *(const float4*)&z[row * DDIM + lane * 4];
  *(float4*)&zq[row * DDIM + lane * 4] = c;

  double s = 0.0, d;
  d = (double)c.x - (double)ze.x; s += d * d;
  d = (double)c.y - (double)ze.y; s += d * d;
  d = (double)c.z - (double)ze.z; s += d * d;
  d = (double)c.w - (double)ze.w; s += d * d;
#pragma unroll
  for (int off = 32; off > 0; off >>= 1) s += __shfl_xor(s, off);

  __shared__ double partial[4];
  if (lane == 0) {
    partial[w] = s;
    atomicAdd(&counts[idx], 1);
  }
  __syncthreads();
  if (t == 0) atomicAdd(mse_acc, partial[0] + partial[1] + partial[2] + partial[3]);
}

// ---------------------------------------------------------------------------
// Kernel 5: scalars (unchanged).
// ---------------------------------------------------------------------------
__global__ __launch_bounds__(256) void finalize_kernel(const int* __restrict__ counts,
                                                       const double* __restrict__ mse_acc,
                                                       float* __restrict__ out) {
  const int t = threadIdx.x;
  double ent = 0.0;
  int used = 0;
#pragma unroll
  for (int i = t; i < KCB; i += 256) {
    int c = counts[i];
    if (c > 0) used++;
    double p = (double)c / (double)NROWS;
    ent += p * log(p + 1e-10);
  }
  __shared__ double se[256];
  __shared__ int    su[256];
  se[t] = ent; su[t] = used;
  __syncthreads();
  for (int s = 128; s > 0; s >>= 1) {
    if (t < s) { se[t] += se[t + s]; su[t] += su[t + s]; }
    __syncthreads();
  }
  if (t == 0) {
    double mse = *mse_acc / ((double)NROWS * (double)DDIM);
    out[OUT_LOSS]  = (float)(1.25 * mse);
    out[OUT_PERP]  = (float)exp(-se[0]);
    out[OUT_USAGE] = (float)((double)su[0] / (double)KCB);
  }
}

// ---------------------------------------------------------------------------
extern "C" void kernel_launch(void* const* d_in, const int* in_sizes, int n_in,
                              void* d_out, int out_size, void* d_ws, size_t ws_size,
                              hipStream_t stream) {
  const float* z  = (const float*)d_in[0];   // [65536][256]
  const float* lb = (const float*)d_in[1];   // [1024][256]
  const float* W  = (const float*)d_in[2];   // [256][256]
  float* out = (float*)d_out;

  const size_t NEEDED_FULL = 0x5200000;      // ~86 MB incl. z_hi/z_lo
  const bool presplit = ws_size >= NEEDED_FULL;

  char* ws = (char*)d_ws;
  ushort* zhi = (ushort*)(ws + 0x0000000);   // 32 MB (presplit only)
  ushort* zlo = (ushort*)(ws + 0x2000000);   // 32 MB (presplit only)
  char* base = ws + (presplit ? 0x4000000 : 0);

  double* cb64   = (double*)(base + 0x0000000);  // 2 MB
  ushort* ch     = (ushort*)(base + 0x0200000);  // 512 KB
  ushort* cl     = (ushort*)(base + 0x0280000);  // 512 KB
  float*  cb32   = (float*) (base + 0x0300000);  // 1 MB
  double* c264   = (double*)(base + 0x0400000);  // 8 KB
  float*  pm1    = (float*) (base + 0x0500000);  // 4 MB
  float*  pm2    = (float*) (base + 0x0900000);  // 4 MB
  int*    pi1    = (int*)   (base + 0x0D00000);  // 4 MB
  int*    idxi   = (int*)   (base + 0x1100000);  // 256 KB
  int*    flagr  = (int*)   (base + 0x1140000);  // 256 KB
  int*    flagc  = (int*)   (base + 0x1180000);  // 4 B
  int*    counts = (int*)   (base + 0x1181000);  // 4 KB
  double* mseacc = (double*)(base + 0x1182000);  // 8 B

  hipMemsetAsync(flagc, 0, 4, stream);
  hipMemsetAsync(counts, 0, KCB * sizeof(int), stream);
  hipMemsetAsync(mseacc, 0, sizeof(double), stream);

  cb_kernel<<<KCB, 256, 0, stream>>>(lb, W, cb64, cb32, c264, ch, cl);
  if (presplit) {
    zsplit_kernel<<<4096, 256, 0, stream>>>(z, zhi, zlo);
    argmax_mfma<true><<<4096, 256, 0, stream>>>(z, zhi, zlo, ch, cl, pm1, pm2, pi1);
  } else {
    argmax_mfma<false><<<4096, 256, 0, stream>>>(z, zhi, zlo, ch, cl, pm1, pm2, pi1);
  }
  reduce_kernel<<<NROWS / 256, 256, 0, stream>>>(pm1, pm2, pi1, out + OUT_IDX, idxi, flagc, flagr);
  refine_kernel<<<512, 256, 0, stream>>>(z, cb64, c264, flagc, flagr, idxi, out + OUT_IDX);
  gather_kernel<<<NROWS / 4, 256, 0, stream>>>(z, cb32, idxi, out + OUT_ZQ, mseacc, counts);
  finalize_kernel<<<1, 256, 0, stream>>>(counts, mseacc, out);
}